// Round 2
// baseline (67.317 us; speedup 1.0000x reference)
//
#include <hip/hip_runtime.h>
#include <math.h>

// QuantumAttentionLayer — analytic collapse.
//
// The reference circuit: H on all qubits -> CNOT chain -> per-qubit RX(data),
// RY(ry_t), RZ(rz_t) -> <Z_i>.
//   * H^n|0> is uniform; the CNOT chain permutes basis states of a uniform
//     state -> no-op.
//   * State remains a product state; RX acts on |+> as a global phase
//     (|+> is the X eigenvector), so the data encoding cancels entirely.
//   * RZ only adds phases; <Z_i> = -sin(ry_theta[h,i]).
// Hence head_out is batch-independent and
//   out[b, j] = sum_k (-sin(ry_flat[k])) * W[j,k] + bias[j]   for all b.
//
// Kernel: 20 threads/block compute the shared 20-float row (redundant per
// block, negligible), then 80 blocks x 256 threads broadcast it to the
// (4096, 20) output with float4 stores (20480 stores total).

#define QA_BATCH 4096
#define QA_NQ    20

__global__ __launch_bounds__(256) void qattn_row_bcast(
    const float* __restrict__ ry_theta,  // (2,10) flat = 20
    const float* __restrict__ W,         // (20,20) row-major
    const float* __restrict__ bias,      // (20,)
    float* __restrict__ out)             // (4096,20) float32
{
    __shared__ float row[QA_NQ];
    const int t = threadIdx.x;

    if (t < QA_NQ) {
        float acc = bias[t];
#pragma unroll
        for (int k = 0; k < QA_NQ; ++k) {
            acc -= sinf(ry_theta[k]) * W[t * QA_NQ + k];
        }
        row[t] = acc;
    }
    __syncthreads();

    const int total4 = QA_BATCH * QA_NQ / 4;  // 20480 float4
    float4* __restrict__ out4 = reinterpret_cast<float4*>(out);
    for (int idx = blockIdx.x * blockDim.x + t; idx < total4;
         idx += gridDim.x * blockDim.x) {
        const int m = (idx % 5) * 4;  // row is 5 float4s wide
        out4[idx] = make_float4(row[m], row[m + 1], row[m + 2], row[m + 3]);
    }
}

extern "C" void kernel_launch(void* const* d_in, const int* in_sizes, int n_in,
                              void* d_out, int out_size, void* d_ws, size_t ws_size,
                              hipStream_t stream) {
    // setup_inputs() order:
    //   0: query (B,20)   [unused — provably no effect on output]
    //   1: key   (B,20)   [unused]
    //   2: value (B,20)   [unused]
    //   3: ry_theta (2,10)
    //   4: rz_theta (2,10) [unused — RZ phases cancel in |.|^2]
    //   5: W (20,20)
    //   6: b (20,)
    const float* ry   = (const float*)d_in[3];
    const float* W    = (const float*)d_in[5];
    const float* bias = (const float*)d_in[6];
    float* out = (float*)d_out;

    const int threads = 256;
    const int blocks  = (QA_BATCH * QA_NQ / 4) / threads;  // 80
    qattn_row_bcast<<<blocks, threads, 0, stream>>>(ry, W, bias, out);
}